// Round 6
// baseline (316.124 us; speedup 1.0000x reference)
//
#include <hip/hip_runtime.h>

// snnTorch Leaky recurrence, reset='subtract':
//   mem_t = 0.95*mem_{t-1} + x_t - spk_{t-1};  spk_t = (mem_t > 1)
// N=8192 independent chains, T=4000 sequential (serial-chain floor:
// 4000 steps x 12 cyc = 48K cyc ~= 20 us).
//
// R4/R5 post-mortem: global_load_lds is unusable at low occupancy — the
// compiler must assume every later ds_read aliases the in-flight DMA and
// emits vmcnt(0) before it, exposing a full ~1200-cyc round trip per DMA.
// R6: stage via VGPRs. 16 coalesced global_load_dwordx4 per 128-step tile
// land in registers (no false LDS dependency); the vmcnt wait sits before
// the ds_write block, which is placed AFTER computing the current tile
// (1536-cyc chain > 900-cyc HBM latency -> loads fully hidden).
// sched_barrier(0) pins region order: [stage loads][compute][ds_write].
// Spikes stay nibble-packed in ws (R4: WRITE 131->4.3 MB); expand kernel
// (massively parallel, coalesced) writes the float output.
//
// Numerics: exact reference rounding ((0.95*mem + x) - r) via __f*_rn, no
// fma contraction — verified absmax 0.0 in R1-R5. Pack order identical to
// R4/R5 (word = col>>3, nibble = (col&7)*4).

namespace {

constexpr int T_LEN = 4000;
constexpr int N_NEU = 8192;
constexpr int RPW   = 32;    // neurons (rows) per wave; 256 blocks -> all CUs
constexpr int TT    = 128;   // timesteps per full tile
constexpr int CT    = TT/4;  // 32 float4 cols
constexpr int TAILC = 8;     // tail tile: 32 steps (4000 = 31*128 + 32)
constexpr int LRS   = 33;    // LDS row stride in float4: 132 dwords = 4 mod 32
                             // -> minimum bank aliasing (8 dw/bank) both dirs
constexpr int QROW  = 128;   // packed row stride in u32 (125 used)
constexpr size_t QBYTES = (size_t)N_NEU * QROW * 4;  // 4 MiB (fits: R4 took this path)

#define SCHED_FENCE() __builtin_amdgcn_sched_barrier(0)

__device__ __forceinline__ unsigned step1(float x, float& mem, float& r) {
    float t = __fmul_rn(0.95f, mem);
    t       = __fadd_rn(t, x);
    mem     = __fsub_rn(t, r);
    bool s  = mem > 1.0f;
    r = s ? 1.0f : 0.0f;      // spike_t == reset_{t+1}
    return s ? 1u : 0u;
}

// Coalesced stage of one C-col tile into VGPRs: instruction k covers rows
// [k*RPI, (k+1)*RPI) x C float4s = 64 lanes x 16 B (contiguous 512 B per row
// segment). C=32: 16 instrs, 2 rows each. C=8 (tail): 4 instrs, 8 rows each.
template <int C>
__device__ __forceinline__ void stage(const float* __restrict__ src, int l,
                                      float4* __restrict__ v) {
    constexpr int RPI = 64 / C;
    constexpr int NI  = RPW / RPI;
    const float* p = src + (size_t)(l / C) * T_LEN + (l % C) * 4;
#pragma unroll
    for (int k = 0; k < NI; ++k)
        v[k] = *reinterpret_cast<const float4*>(p + (size_t)k * RPI * T_LEN);
}

template <int C>
__device__ __forceinline__ void dswrite(float4* __restrict__ buf, int l,
                                        const float4* __restrict__ v) {
    constexpr int RPI = 64 / C;
    constexpr int NI  = RPW / RPI;
    const int row0 = l / C, col = l % C;
#pragma unroll
    for (int k = 0; k < NI; ++k)
        buf[(k * RPI + row0) * LRS + col] = v[k];
}

// Compute C float4-steps for this lane's neuron (row l&31; lanes 32-63
// duplicate via same-address LDS broadcast). Pack 4 spike bits per nibble.
template <int C>
__device__ __forceinline__ void compute(const float4* __restrict__ buf, int lrow,
                                        float& mem, float& r,
                                        unsigned* __restrict__ qword, bool qen) {
    const float4* irow = buf + lrow * LRS;
    constexpr int W = (C + 7) / 8;
    unsigned u[W];
#pragma unroll
    for (int w = 0; w < W; ++w) u[w] = 0;
#pragma unroll
    for (int c = 0; c < C; ++c) {
        float4 v = irow[c];
        unsigned b;
        b  = step1(v.x, mem, r);
        b |= step1(v.y, mem, r) << 1;
        b |= step1(v.z, mem, r) << 2;
        b |= step1(v.w, mem, r) << 3;
        u[c >> 3] |= b << ((c & 7) * 4);
    }
    if (qen) {
        if (C == 32)
            *reinterpret_cast<uint4*>(qword) = make_uint4(u[0], u[1], u[2], u[3]);
        else
            qword[0] = u[0];
    }
}

__global__ __launch_bounds__(64, 1)
void snn_scan(const float* __restrict__ x, unsigned* __restrict__ q) {
    __shared__ float4 bufA[RPW * LRS];   // 16896 B
    __shared__ float4 bufB[RPW * LRS];   // 16896 B
    const int l    = threadIdx.x;
    const int lrow = l & (RPW - 1);
    const size_t n0 = (size_t)blockIdx.x * RPW;
    const float* xb = x + n0 * T_LEN;
    unsigned* qn = q + (n0 + lrow) * QROW;
    const bool qen = (l < RPW);

    float mem = 0.0f;   // mem_0 = 0
    float r   = 0.0f;   // reset_1 = H(0-1) = 0
    float4 v[16];

    // Prologue: tile 0 -> regs -> LDS A (one exposed round trip, once).
    stage<CT>(xb, l, v);
    dswrite<CT>(bufA, l, v);

    // Tiles 0..29 in ping-pong pairs. Iteration d: compute 2d (A), 2d+1 (B).
#pragma unroll 1
    for (int d = 0; d < 15; ++d) {
        const int t = 2 * d;
        stage<CT>(xb + (t + 1) * TT, l, v);   // loads in flight across compute
        SCHED_FENCE();
        compute<CT>(bufA, lrow, mem, r, qn + t * 4, qen);
        SCHED_FENCE();
        dswrite<CT>(bufB, l, v);              // vmcnt wait here (already drained)

        stage<CT>(xb + (t + 2) * TT, l, v);
        SCHED_FENCE();
        compute<CT>(bufB, lrow, mem, r, qn + (t + 1) * 4, qen);
        SCHED_FENCE();
        dswrite<CT>(bufA, l, v);
    }
    // A holds tile 30. Stage tail (32 steps), compute 30, write tail, compute.
    stage<TAILC>(xb + 31 * TT, l, v);
    SCHED_FENCE();
    compute<CT>(bufA, lrow, mem, r, qn + 30 * 4, qen);
    SCHED_FENCE();
    dswrite<TAILC>(bufB, l, v);
    compute<TAILC>(bufB, lrow, mem, r, qn + 124, qen);  // word 124, cols 992..999
}

// Expand packed nibbles -> float spikes, fully coalesced float4 writes.
// 8192*1000 float4s = 32000 blocks x 256 threads exactly.
__global__ __launch_bounds__(256)
void snn_expand(const unsigned* __restrict__ q, float* __restrict__ out) {
    const unsigned i = blockIdx.x * 256 + threadIdx.x;  // float4 index
    const unsigned n = i / 1000u;                       // neuron row
    const unsigned c = i - n * 1000u;                   // float4 col
    const unsigned w = q[n * QROW + (c >> 3)];
    const unsigned nib = w >> ((c & 7u) * 4u);
    float4 f;
    f.x = (nib & 1u) ? 1.0f : 0.0f;
    f.y = (nib & 2u) ? 1.0f : 0.0f;
    f.z = (nib & 4u) ? 1.0f : 0.0f;
    f.w = (nib & 8u) ? 1.0f : 0.0f;
    reinterpret_cast<float4*>(out)[i] = f;
}

} // namespace

extern "C" void kernel_launch(void* const* d_in, const int* in_sizes, int n_in,
                              void* d_out, int out_size, void* d_ws, size_t ws_size,
                              hipStream_t stream) {
    const float* x = (const float*)d_in[0];
    float* out     = (float*)d_out;
    unsigned* q    = (unsigned*)d_ws;   // >= 4 MiB (R4/R5 verified this path)
    snn_scan<<<dim3(N_NEU / RPW), dim3(64), 0, stream>>>(x, q);
    snn_expand<<<dim3(32000), dim3(256), 0, stream>>>(q, out);
}

// Round 7
// 259.159 us; speedup vs baseline: 1.2198x; 1.2198x over previous
//
#include <hip/hip_runtime.h>

// snnTorch Leaky recurrence, reset='subtract':
//   mem_t = 0.95*mem_{t-1} + x_t - spk_{t-1};  spk_t = (mem_t > 1)
// N=8192 independent chains, T=4000 sequential.
//
// R6 post-mortem: every structure so far cost ~330 cyc per float4 consumed =
// one exposed memory latency per 16B quantum. LDS round-trips can't fix it:
// staged VGPRs starve the scheduler (VGPR 132) so ds_reads go just-in-time.
// R7: no LDS. Per-lane row streaming with an EXPLICIT 16-deep float4 register
// ring: slot j is refilled at phase j of one 16-group half and consumed at
// phase j of the next half -> uniform 64-step (~900 cyc) flight per load,
// covering HBM/LLC latency. Spikes nibble-packed (R4 layout, verified) so
// stores are 16B/lane/128-steps and the vmem queue stays shallow; the
// massively-parallel expand kernel writes the 131 MB float output coalesced.
//
// Numerics: exact reference rounding ((0.95*mem + x) - r) via __f*_rn, no
// fma contraction — verified absmax 0.0 in R1-R6. Pack layout identical to
// R4-R6 (word = g>>3, nibble = (g&7)*4), expand kernel unchanged.

namespace {

constexpr int T_LEN = 4000;
constexpr int N_NEU = 8192;
constexpr int QROW  = 128;   // packed row stride in u32 (125 used)
constexpr size_t QBYTES = (size_t)N_NEU * QROW * 4;  // 4 MiB ws (verified fits)

__device__ __forceinline__ unsigned step1(float x, float& mem, float& r) {
    float t = __fmul_rn(0.95f, mem);
    t       = __fadd_rn(t, x);
    mem     = __fsub_rn(t, r);
    bool s  = mem > 1.0f;
    r = s ? 1.0f : 0.0f;      // spike_t == reset_{t+1}
    return s ? 1u : 0u;
}

// Consume ring slots 0..15 (groups g0..g0+15 = 64 steps); refill slot j with
// group g0+16+j for j < PF. p = lane's row pointer at group g0 (floats).
// Refill issued at phase j, consumed at phase j of the NEXT half -> every
// load gets exactly 64 steps (~900 cyc) of flight. sched_barrier pins halves.
template <int PF>
__device__ __forceinline__ void half16(const float* __restrict__ p,
                                       float4* __restrict__ ring,
                                       float& mem, float& r,
                                       unsigned& u0, unsigned& u1) {
    u0 = 0; u1 = 0;
#pragma unroll
    for (int j = 0; j < 16; ++j) {
        float4 v = ring[j];
        if (j < PF)   // refill before compute: issue slot early, consume late
            ring[j] = *reinterpret_cast<const float4*>(p + 64 + 4 * j);
        unsigned b;
        b  = step1(v.x, mem, r);
        b |= step1(v.y, mem, r) << 1;
        b |= step1(v.z, mem, r) << 2;
        b |= step1(v.w, mem, r) << 3;
        const unsigned sh = (j & 7) * 4;
        if (j < 8) u0 |= b << sh; else u1 |= b << sh;
    }
    __builtin_amdgcn_sched_barrier(0);   // keep refills inside their half
}

__global__ __launch_bounds__(64, 1)
void snn_scan(const float* __restrict__ x, unsigned* __restrict__ q) {
    const int l = threadIdx.x;
    const size_t n = (size_t)blockIdx.x * 64 + l;   // this lane's neuron
    const float* p = x + n * T_LEN;                 // row base (16000B, 16B-aligned)
    unsigned* qn = q + n * QROW;

    float mem = 0.0f;   // mem_0 = 0
    float r   = 0.0f;   // reset_1 = H(0-1) = 0

    float4 ring[16];    // 64 VGPRs, all indices static
#pragma unroll
    for (int j = 0; j < 16; ++j)
        ring[j] = *reinterpret_cast<const float4*>(p + 4 * j);

    unsigned w0, w1, w2, w3;
    // Main: 30 pairs x 32 groups = groups 0..959 (words 0..119).
#pragma unroll 1
    for (int k = 0; k < 30; ++k) {
        half16<16>(p,      ring, mem, r, w0, w1);
        half16<16>(p + 64, ring, mem, r, w2, w3);
        *reinterpret_cast<uint4*>(qn) = make_uint4(w0, w1, w2, w3);
        qn += 4;
        p  += 128;
    }
    // Epilogue: groups 960..975 (pf 976..991), 976..991 (pf 992..999).
    half16<16>(p,      ring, mem, r, w0, w1);
    half16<8 >(p + 64, ring, mem, r, w2, w3);
    *reinterpret_cast<uint4*>(qn) = make_uint4(w0, w1, w2, w3);  // words 120..123
    // Final 8 groups (992..999) from ring[0..7] -> word 124.
    unsigned u = 0;
#pragma unroll
    for (int j = 0; j < 8; ++j) {
        float4 v = ring[j];
        unsigned b;
        b  = step1(v.x, mem, r);
        b |= step1(v.y, mem, r) << 1;
        b |= step1(v.z, mem, r) << 2;
        b |= step1(v.w, mem, r) << 3;
        u |= b << (j * 4);
    }
    qn[4] = u;
}

// Expand packed nibbles -> float spikes, fully coalesced float4 writes.
// 8192*1000 float4s = 32000 blocks x 256 threads exactly.
__global__ __launch_bounds__(256)
void snn_expand(const unsigned* __restrict__ q, float* __restrict__ out) {
    const unsigned i = blockIdx.x * 256 + threadIdx.x;  // float4 index
    const unsigned n = i / 1000u;                       // neuron row
    const unsigned c = i - n * 1000u;                   // float4 col
    const unsigned w = q[n * QROW + (c >> 3)];
    const unsigned nib = w >> ((c & 7u) * 4u);
    float4 f;
    f.x = (nib & 1u) ? 1.0f : 0.0f;
    f.y = (nib & 2u) ? 1.0f : 0.0f;
    f.z = (nib & 4u) ? 1.0f : 0.0f;
    f.w = (nib & 8u) ? 1.0f : 0.0f;
    reinterpret_cast<float4*>(out)[i] = f;
}

} // namespace

extern "C" void kernel_launch(void* const* d_in, const int* in_sizes, int n_in,
                              void* d_out, int out_size, void* d_ws, size_t ws_size,
                              hipStream_t stream) {
    const float* x = (const float*)d_in[0];
    float* out     = (float*)d_out;
    unsigned* q    = (unsigned*)d_ws;   // >= 4 MiB (verified R4-R6)
    snn_scan<<<dim3(N_NEU / 64), dim3(64), 0, stream>>>(x, q);
    snn_expand<<<dim3(32000), dim3(256), 0, stream>>>(q, out);
}